// Round 12
// baseline (242.110 us; speedup 1.0000x reference)
//
#include <hip/hip_runtime.h>

#define N_NODES 65536
#define N_EDGES 1048576
#define NB 256            // coarse buckets = dst >> 8
#define CAP 4608          // per-bucket capacity: mean 4096 + 8 sigma (binomial)
#define EPB_A 4096        // edges per block in bin pass
#define BLK_A (N_EDGES / EPB_A)   // 256
#define EPT_A (EPB_A / 256)       // 16 edges per thread (256-thread binpass)
#define GEMM_BLK (N_NODES / 64)   // 1024 gemm1 node-blocks

typedef __attribute__((ext_vector_type(8))) short short8v;   // 8 bf16 (4 VGPRs)
typedef __attribute__((ext_vector_type(4))) float float4v;   // MFMA C/D

// fp32 -> bf16 round-to-nearest-even
__device__ __forceinline__ unsigned short f2bf(float f) {
  unsigned u = __float_as_uint(f);
  unsigned r = u + 0x7FFFu + ((u >> 16) & 1u);
  return (unsigned short)(r >> 16);
}
__device__ __forceinline__ float bflo(unsigned u) { return __uint_as_float(u << 16); }
__device__ __forceinline__ float bfhi(unsigned u) { return __uint_as_float(u & 0xFFFF0000u); }

// ---------------------------------------------------------------------------
// JAX threefry2x32, partitionable path: bits[i] = x0^x1 of
// threefry2x32(key=(0,42), counter=(0,i)); keep = MSB==0.  [verified R1]
// ---------------------------------------------------------------------------
__device__ __forceinline__ bool keep_mask(unsigned idx) {
  const unsigned k0 = 0u, k1 = 42u;
  const unsigned k2 = 0x1BD11BDAu ^ k0 ^ k1;
  unsigned x0 = 0u;
  unsigned x1 = idx;
  x0 += k0; x1 += k1;
#define TF_ROUND(r) { x0 += x1; x1 = (x1 << (r)) | (x1 >> (32 - (r))); x1 ^= x0; }
  TF_ROUND(13) TF_ROUND(15) TF_ROUND(26) TF_ROUND(6)
  x0 += k1; x1 += k2 + 1u;
  TF_ROUND(17) TF_ROUND(29) TF_ROUND(16) TF_ROUND(24)
  x0 += k2; x1 += k0 + 2u;
  TF_ROUND(13) TF_ROUND(15) TF_ROUND(26) TF_ROUND(6)
  x0 += k0; x1 += k1 + 3u;
  TF_ROUND(17) TF_ROUND(29) TF_ROUND(16) TF_ROUND(24)
  x0 += k1; x1 += k2 + 4u;
  TF_ROUND(13) TF_ROUND(15) TF_ROUND(26) TF_ROUND(6)
  x0 += k2; x1 += k0 + 5u;
#undef TF_ROUND
  return ((x0 ^ x1) & 0x80000000u) == 0u;
}

// ===========================================================================
// binpass_body: bucket multisplit at 256 threads (R0-proven shape, R10's
// compressed val/key outputs).  Contiguous per-block run + cnt/lofs mats.
// LDS raw: stage_val[4096] @0 (16384) | stage_key[4096] @16384 (4096) |
// cnt @20480 | lofs @21504 | lcur @22528 -> 23552 B.
// ===========================================================================
__device__ __forceinline__ void binpass_body(unsigned char* raw, int b,
                                             const int* __restrict__ ei,
                                             const float* __restrict__ ew,
                                             unsigned* __restrict__ val2,
                                             unsigned char* __restrict__ key2,
                                             unsigned* __restrict__ cnt_mat,
                                             unsigned* __restrict__ lofs_mat) {
  unsigned* stage_val      = (unsigned*)raw;
  unsigned char* stage_key = raw + 16384;
  unsigned* cnt  = (unsigned*)(raw + 20480);
  unsigned* lofs = cnt + NB;
  unsigned* lcur = lofs + NB;
  const int t = threadIdx.x;
  const int e0 = b * EPB_A;
  cnt[t] = 0u;
  lcur[t] = 0u;
  __syncthreads();
  unsigned pv[EPT_A], pd[EPT_A];
#pragma unroll
  for (int j = 0; j < EPT_A; ++j) {
    int e = e0 + t + j * 256;
    unsigned s = (unsigned)ei[e];
    unsigned d = (unsigned)ei[N_EDGES + e];
    pv[j] = s | ((unsigned)f2bf(ew[e]) << 16);
    pd[j] = d;
    atomicAdd(&cnt[d >> 8], 1u);
  }
  __syncthreads();
  lofs[t] = cnt[t];
  __syncthreads();
  for (int d = 1; d < NB; d <<= 1) {
    unsigned u = (t >= d) ? lofs[t - d] : 0u;
    __syncthreads();
    lofs[t] += u;
    __syncthreads();
  }
  lofs[t] -= cnt[t];                    // exclusive prefix
  cnt_mat[(unsigned)b * NB + t]  = cnt[t];
  lofs_mat[(unsigned)b * NB + t] = lofs[t];
  __syncthreads();
#pragma unroll
  for (int j = 0; j < EPT_A; ++j) {
    unsigned bk = pd[j] >> 8;
    unsigned slot = lofs[bk] + atomicAdd(&lcur[bk], 1u);
    stage_val[slot] = pv[j];
    stage_key[slot] = (unsigned char)(pd[j] & 255u);
  }
  __syncthreads();
  unsigned* dv = val2 + (size_t)b * EPB_A;
  unsigned char* dk = key2 + (size_t)b * EPB_A;
  for (int s = t; s < EPB_A; s += 256) { dv[s] = stage_val[s]; dk[s] = stage_key[s]; }
}

// ===========================================================================
// gemm1_body: h1 = x @ W1 via bf16 MFMA 16x16x32; h1 stored bf16.
// Bs staged DIRECTLY from fp32 W1 (transpose+f2bf on the fly; W1 is 76 KB,
// L2-resident) — no Wt intermediate, no ordering dependency.
// LDS raw: As[64][72] @0 (9216), Bs[64][72] @9216 -> 18432 B.
// ===========================================================================
__device__ __forceinline__ void gemm1_body(unsigned char* smraw, int nb,
                                           const float* __restrict__ x,
                                           const float* __restrict__ W1,
                                           unsigned short* __restrict__ h1b) {
  unsigned short (*As)[72] = (unsigned short (*)[72])smraw;
  unsigned short (*Bs)[72] = (unsigned short (*)[72])(smraw + 9216);
  const int t = threadIdx.x;
  const int node0 = nb * 64;
  const int wave = t >> 6, lane = t & 63;
  const int quad = lane >> 4, l16 = lane & 15;
  float4v acc[4] = {{0.f,0.f,0.f,0.f},{0.f,0.f,0.f,0.f},{0.f,0.f,0.f,0.f},{0.f,0.f,0.f,0.f}};

  for (int kt = 0; kt < 5; ++kt) {
    const int k0 = kt * 64;
    for (int f = t; f < 1024; f += 256) {
      int node = f >> 4;
      int k = (f & 15) * 4;
      uint2 packed;
      if (k0 + k < 300) {
        float4 v = *(const float4*)(x + (size_t)(node0 + node) * 300 + k0 + k);
        packed.x = (unsigned)f2bf(v.x) | ((unsigned)f2bf(v.y) << 16);
        packed.y = (unsigned)f2bf(v.z) | ((unsigned)f2bf(v.w) << 16);
      } else {
        packed.x = 0u; packed.y = 0u;
      }
      *(uint2*)&As[node][k] = packed;
    }
    for (int f = t; f < 512; f += 256) {
      int ch = f >> 3;
      int kq = f & 7;
      unsigned short tmp[8];
#pragma unroll
      for (int m = 0; m < 8; ++m) {
        int k = k0 + kq * 8 + m;
        tmp[m] = (k < 300) ? f2bf(W1[(size_t)k * 64 + ch]) : (unsigned short)0;
      }
      uint4 v;
      v.x = (unsigned)tmp[0] | ((unsigned)tmp[1] << 16);
      v.y = (unsigned)tmp[2] | ((unsigned)tmp[3] << 16);
      v.z = (unsigned)tmp[4] | ((unsigned)tmp[5] << 16);
      v.w = (unsigned)tmp[6] | ((unsigned)tmp[7] << 16);
      *(uint4*)&Bs[ch][kq * 8] = v;
    }
    __syncthreads();
    short8v a0 = *(const short8v*)&As[wave * 16 + l16][quad * 8];
    short8v a1 = *(const short8v*)&As[wave * 16 + l16][32 + quad * 8];
#pragma unroll
    for (int nt = 0; nt < 4; ++nt) {
      short8v b0 = *(const short8v*)&Bs[nt * 16 + l16][quad * 8];
      short8v b1 = *(const short8v*)&Bs[nt * 16 + l16][32 + quad * 8];
      acc[nt] = __builtin_amdgcn_mfma_f32_16x16x32_bf16(a0, b0, acc[nt], 0, 0, 0);
      acc[nt] = __builtin_amdgcn_mfma_f32_16x16x32_bf16(a1, b1, acc[nt], 0, 0, 0);
    }
    __syncthreads();
  }
#pragma unroll
  for (int nt = 0; nt < 4; ++nt) {
#pragma unroll
    for (int r = 0; r < 4; ++r) {
      h1b[(size_t)(node0 + wave * 16 + quad * 4 + r) * 64 + nt * 16 + l16] = f2bf(acc[nt][r]);
    }
  }
}

// ===========================================================================
// binpass_gemm1: blocks [0,256) = binpass; [256,1280) = gemm1.  Disjoint
// inputs -> true overlap.  LDS union 23552 B.
// ===========================================================================
__global__ __launch_bounds__(256) void binpass_gemm1(const int* __restrict__ ei,
                                                     const float* __restrict__ ew,
                                                     unsigned* __restrict__ val2,
                                                     unsigned char* __restrict__ key2,
                                                     unsigned* __restrict__ cnt_mat,
                                                     unsigned* __restrict__ lofs_mat,
                                                     const float* __restrict__ x,
                                                     const float* __restrict__ W1,
                                                     unsigned short* __restrict__ h1b) {
  __shared__ __align__(16) unsigned char sm[23552];
  if (blockIdx.x < BLK_A) {
    binpass_body(sm, blockIdx.x, ei, ew, val2, key2, cnt_mat, lofs_mat);
  } else {
    gemm1_body(sm, blockIdx.x - BLK_A, x, W1, h1b);
  }
}

// ===========================================================================
// sortagg1: ONE block (1024 thr) per bucket.  Phase A: gather segments,
// counting-sort the bucket's edges IN LDS; dump sortedc/offs_p (coalesced)
// for aggregate2.  Phase B: aggregate the bucket's 256 nodes straight from
// the sorted LDS edge list, fused b1+relu+dropout+gemm2 epilogue -> g32u.
// R12 FIX: staging arrays sized CAP (4608), not 4096 — bucket occupancy is
// Binomial(1M,1/256), mean 4096, so 4096 overflowed half the time (R11 bug).
// LDS raw layout (54080 B total):
//   uval[CAP]u32 @0      (18432)  } phase A staging, dead after scatter
//   ukey[CAP]u8  @18432  (4608)   }   -> h2[64][68]f32 aliases @0 (17408)
//   sval[CAP]u32 @23040  (18432)  sorted payload (src|bf16w)
//   tables @41472: scnt_s|sbase_s|mst_s|cnt|cur|stn|ctn (7*1024 = 7168)
//   w2t[20*68]f32 @48640 (5440) -> end 54080
// ===========================================================================
__global__ __launch_bounds__(1024) void sortagg1(const unsigned* __restrict__ cnt_mat,
                                                 const unsigned* __restrict__ lofs_mat,
                                                 const unsigned* __restrict__ val2,
                                                 const unsigned char* __restrict__ key2,
                                                 unsigned* __restrict__ sortedc,
                                                 unsigned* __restrict__ offs_p,
                                                 const unsigned short* __restrict__ h1b,
                                                 const float* __restrict__ b1,
                                                 const float* __restrict__ W2,
                                                 unsigned* __restrict__ g32u) {
  __shared__ __align__(16) unsigned char raw[54080];
  unsigned*      uval   = (unsigned*)raw;
  unsigned char* ukey   = raw + 18432;
  unsigned*      sval   = (unsigned*)(raw + 23040);
  unsigned* scnt_s  = (unsigned*)(raw + 41472);
  unsigned* sbase_s = scnt_s + NB;
  unsigned* mst_s   = sbase_s + NB;
  unsigned* cnt     = mst_s + NB;
  unsigned* cur     = cnt + NB;
  unsigned* stn     = cur + NB;
  unsigned* ctn     = stn + NB;
  float*    h2      = (float*)raw;            // aliases uval (phase B)
  float*    w2t     = (float*)(raw + 48640);
  const int t = threadIdx.x;
  const int b = blockIdx.x;
  const unsigned lo = (unsigned)b * CAP;

  // w2t load (region untouched by phase A)
  for (int i = t; i < 20 * 64; i += 1024) {
    int row = i >> 6, col = i & 63;
    w2t[row * 68 + col] = W2[col * 20 + row];
  }
  // ---- Phase A: segment scan + gather + counting sort (in LDS) ----
  if (t < NB) {
    unsigned sc = cnt_mat[(unsigned)t * NB + b];
    scnt_s[t]  = sc;
    sbase_s[t] = (unsigned)t * EPB_A + lofs_mat[(unsigned)t * NB + b];
    cnt[t] = 0u;
    cur[t] = sc;
  }
  __syncthreads();
  for (int d = 1; d < NB; d <<= 1) {
    unsigned u = (t < NB && t >= d) ? cur[t - d] : 0u;
    __syncthreads();
    if (t < NB) cur[t] += u;
    __syncthreads();
  }
  if (t < NB) mst_s[t] = cur[t] - scnt_s[t];
  __syncthreads();
  const unsigned n_edges = cur[NB - 1];
  // cooperative gather: 64 groups x 16 lanes; group g copies segs g,g+64,...
  const int g = t >> 4, j0 = t & 15;
  for (int seg = g; seg < NB; seg += 64) {
    const unsigned sc = scnt_s[seg];
    const unsigned sb = sbase_s[seg];
    const unsigned ms = mst_s[seg];
    for (unsigned j = (unsigned)j0; j < sc; j += 16) {
      uval[ms + j] = val2[sb + j];
      ukey[ms + j] = key2[sb + j];
    }
  }
  __syncthreads();
  for (unsigned i = t; i < n_edges; i += 1024)
    atomicAdd(&cnt[ukey[i]], 1u);
  __syncthreads();
  if (t < NB) cur[t] = cnt[t];
  __syncthreads();
  for (int d = 1; d < NB; d <<= 1) {
    unsigned u = (t < NB && t >= d) ? cur[t - d] : 0u;
    __syncthreads();
    if (t < NB) cur[t] += u;
    __syncthreads();
  }
  if (t < NB) {
    unsigned excl = cur[t] - cnt[t];
    stn[t] = excl;
    ctn[t] = cnt[t];
    offs_p[b * NB + t] = (lo + excl) | (cnt[t] << 21);
    cur[t] = excl;                     // scatter cursors
  }
  __syncthreads();
  for (unsigned i = t; i < n_edges; i += 1024) {
    unsigned k = ukey[i];
    unsigned p = atomicAdd(&cur[k], 1u);
    sval[p] = uval[i];
  }
  __syncthreads();
  // coalesced dump for aggregate2
  for (unsigned i = t; i < n_edges; i += 1024) sortedc[lo + i] = sval[i];
  __syncthreads();                     // uval/ukey dead; h2 aliases them now

  // ---- Phase B: aggregate 256 nodes from sorted LDS edges (4 chunks) ----
  const int n = t >> 4, cg = t & 15;   // 64 nodes/chunk x 16 lanes
  for (int chunk = 0; chunk < 4; ++chunk) {
    const int ln = chunk * 64 + n;
    const unsigned node = (unsigned)b * 256u + (unsigned)ln;
    const unsigned s = stn[ln];
    const unsigned e_end = s + ctn[ln];
    float4 acc = *(const float4*)(b1 + cg * 4);
    unsigned i = s;
    for (; i + 8 <= e_end; i += 8) {
      unsigned e0 = sval[i],     e1 = sval[i + 1], e2 = sval[i + 2], e3 = sval[i + 3];
      unsigned e4 = sval[i + 4], e5 = sval[i + 5], e6 = sval[i + 6], e7 = sval[i + 7];
      uint2 v0 = *(const uint2*)(h1b + ((size_t)(e0 & 0xFFFFu)) * 64 + cg * 4);
      uint2 v1 = *(const uint2*)(h1b + ((size_t)(e1 & 0xFFFFu)) * 64 + cg * 4);
      uint2 v2 = *(const uint2*)(h1b + ((size_t)(e2 & 0xFFFFu)) * 64 + cg * 4);
      uint2 v3 = *(const uint2*)(h1b + ((size_t)(e3 & 0xFFFFu)) * 64 + cg * 4);
      uint2 v4 = *(const uint2*)(h1b + ((size_t)(e4 & 0xFFFFu)) * 64 + cg * 4);
      uint2 v5 = *(const uint2*)(h1b + ((size_t)(e5 & 0xFFFFu)) * 64 + cg * 4);
      uint2 v6 = *(const uint2*)(h1b + ((size_t)(e6 & 0xFFFFu)) * 64 + cg * 4);
      uint2 v7 = *(const uint2*)(h1b + ((size_t)(e7 & 0xFFFFu)) * 64 + cg * 4);
      float w0 = bfhi(e0), w1 = bfhi(e1), w2 = bfhi(e2), w3 = bfhi(e3);
      float w4 = bfhi(e4), w5 = bfhi(e5), w6 = bfhi(e6), w7 = bfhi(e7);
      acc.x = fmaf(w0, bflo(v0.x), acc.x); acc.y = fmaf(w0, bfhi(v0.x), acc.y);
      acc.z = fmaf(w0, bflo(v0.y), acc.z); acc.w = fmaf(w0, bfhi(v0.y), acc.w);
      acc.x = fmaf(w1, bflo(v1.x), acc.x); acc.y = fmaf(w1, bfhi(v1.x), acc.y);
      acc.z = fmaf(w1, bflo(v1.y), acc.z); acc.w = fmaf(w1, bfhi(v1.y), acc.w);
      acc.x = fmaf(w2, bflo(v2.x), acc.x); acc.y = fmaf(w2, bfhi(v2.x), acc.y);
      acc.z = fmaf(w2, bflo(v2.y), acc.z); acc.w = fmaf(w2, bfhi(v2.y), acc.w);
      acc.x = fmaf(w3, bflo(v3.x), acc.x); acc.y = fmaf(w3, bfhi(v3.x), acc.y);
      acc.z = fmaf(w3, bflo(v3.y), acc.z); acc.w = fmaf(w3, bfhi(v3.y), acc.w);
      acc.x = fmaf(w4, bflo(v4.x), acc.x); acc.y = fmaf(w4, bfhi(v4.x), acc.y);
      acc.z = fmaf(w4, bflo(v4.y), acc.z); acc.w = fmaf(w4, bfhi(v4.y), acc.w);
      acc.x = fmaf(w5, bflo(v5.x), acc.x); acc.y = fmaf(w5, bfhi(v5.x), acc.y);
      acc.z = fmaf(w5, bflo(v5.y), acc.z); acc.w = fmaf(w5, bfhi(v5.y), acc.w);
      acc.x = fmaf(w6, bflo(v6.x), acc.x); acc.y = fmaf(w6, bfhi(v6.x), acc.y);
      acc.z = fmaf(w6, bflo(v6.y), acc.z); acc.w = fmaf(w6, bfhi(v6.y), acc.w);
      acc.x = fmaf(w7, bflo(v7.x), acc.x); acc.y = fmaf(w7, bfhi(v7.x), acc.y);
      acc.z = fmaf(w7, bflo(v7.y), acc.z); acc.w = fmaf(w7, bfhi(v7.y), acc.w);
    }
    for (; i < e_end; ++i) {
      unsigned e0 = sval[i];
      uint2 v0 = *(const uint2*)(h1b + ((size_t)(e0 & 0xFFFFu)) * 64 + cg * 4);
      float w0 = bfhi(e0);
      acc.x = fmaf(w0, bflo(v0.x), acc.x); acc.y = fmaf(w0, bfhi(v0.x), acc.y);
      acc.z = fmaf(w0, bflo(v0.y), acc.z); acc.w = fmaf(w0, bfhi(v0.y), acc.w);
    }
    const unsigned gi = node * 64u + (unsigned)cg * 4u;
    float r[4] = {acc.x, acc.y, acc.z, acc.w};
#pragma unroll
    for (int j = 0; j < 4; ++j) {
      float v = fmaxf(r[j], 0.0f);
      h2[n * 68 + cg * 4 + j] = keep_mask(gi + j) ? v * 2.0f : 0.0f;
    }
    __syncthreads();
    // gemm2 tail: lane cg computes ch {2cg, 2cg+1}; pads (cg>=10) as 0
    float d0 = 0.0f, d1 = 0.0f;
    if (cg < 10) {
      const int c0 = cg * 2, c1 = cg * 2 + 1;
#pragma unroll
      for (int k = 0; k < 64; k += 4) {
        float4 hv = *(const float4*)(&h2[n * 68 + k]);
        float4 w0 = *(const float4*)(&w2t[c0 * 68 + k]);
        float4 w1 = *(const float4*)(&w2t[c1 * 68 + k]);
        d0 = fmaf(hv.x, w0.x, d0); d0 = fmaf(hv.y, w0.y, d0);
        d0 = fmaf(hv.z, w0.z, d0); d0 = fmaf(hv.w, w0.w, d0);
        d1 = fmaf(hv.x, w1.x, d1); d1 = fmaf(hv.y, w1.y, d1);
        d1 = fmaf(hv.z, w1.z, d1); d1 = fmaf(hv.w, w1.w, d1);
      }
    }
    unsigned packed = (cg < 10) ? ((unsigned)f2bf(d0) | ((unsigned)f2bf(d1) << 16)) : 0u;
    g32u[(size_t)node * 16 + cg] = packed;
    __syncthreads();                   // h2 reused next chunk
  }
}

// ===========================================================================
// aggregate2: out[n][c] = b2[c] + sum_e w * g[src][c]   (verbatim R6)
// ===========================================================================
__global__ __launch_bounds__(256) void aggregate2(const unsigned* __restrict__ offs_p,
                                                  const unsigned* __restrict__ sortedc,
                                                  const unsigned* __restrict__ g32u,
                                                  const float* __restrict__ b2,
                                                  float* __restrict__ out) {
  const int t = threadIdx.x;
  const int n = blockIdx.x * 16 + (t >> 4);
  const int cg = t & 15;
  const unsigned op = offs_p[n];
  const unsigned s = op & 0x1FFFFFu;
  const unsigned e_end = s + (op >> 21);
  float ax = 0.0f, ay = 0.0f;
  unsigned i = s;
  for (; i + 8 <= e_end; i += 8) {
    unsigned e0 = sortedc[i],     e1 = sortedc[i + 1], e2 = sortedc[i + 2], e3 = sortedc[i + 3];
    unsigned e4 = sortedc[i + 4], e5 = sortedc[i + 5], e6 = sortedc[i + 6], e7 = sortedc[i + 7];
    unsigned v0 = g32u[(size_t)(e0 & 0xFFFFu) * 16 + cg];
    unsigned v1 = g32u[(size_t)(e1 & 0xFFFFu) * 16 + cg];
    unsigned v2 = g32u[(size_t)(e2 & 0xFFFFu) * 16 + cg];
    unsigned v3 = g32u[(size_t)(e3 & 0xFFFFu) * 16 + cg];
    unsigned v4 = g32u[(size_t)(e4 & 0xFFFFu) * 16 + cg];
    unsigned v5 = g32u[(size_t)(e5 & 0xFFFFu) * 16 + cg];
    unsigned v6 = g32u[(size_t)(e6 & 0xFFFFu) * 16 + cg];
    unsigned v7 = g32u[(size_t)(e7 & 0xFFFFu) * 16 + cg];
    float w0 = bfhi(e0), w1 = bfhi(e1), w2 = bfhi(e2), w3 = bfhi(e3);
    float w4 = bfhi(e4), w5 = bfhi(e5), w6 = bfhi(e6), w7 = bfhi(e7);
    ax = fmaf(w0, bflo(v0), ax); ay = fmaf(w0, bfhi(v0), ay);
    ax = fmaf(w1, bflo(v1), ax); ay = fmaf(w1, bfhi(v1), ay);
    ax = fmaf(w2, bflo(v2), ax); ay = fmaf(w2, bfhi(v2), ay);
    ax = fmaf(w3, bflo(v3), ax); ay = fmaf(w3, bfhi(v3), ay);
    ax = fmaf(w4, bflo(v4), ax); ay = fmaf(w4, bfhi(v4), ay);
    ax = fmaf(w5, bflo(v5), ax); ay = fmaf(w5, bfhi(v5), ay);
    ax = fmaf(w6, bflo(v6), ax); ay = fmaf(w6, bfhi(v6), ay);
    ax = fmaf(w7, bflo(v7), ax); ay = fmaf(w7, bfhi(v7), ay);
  }
  for (; i < e_end; ++i) {
    unsigned e0 = sortedc[i];
    unsigned v0 = g32u[(size_t)(e0 & 0xFFFFu) * 16 + cg];
    float w0 = bfhi(e0);
    ax = fmaf(w0, bflo(v0), ax); ay = fmaf(w0, bfhi(v0), ay);
  }
  if (cg < 10) {
    float2 o = make_float2(ax + b2[cg * 2], ay + b2[cg * 2 + 1]);
    *(float2*)(out + (size_t)n * 20 + cg * 2) = o;
  }
}

extern "C" void kernel_launch(void* const* d_in, const int* in_sizes, int n_in,
                              void* d_out, int out_size, void* d_ws, size_t ws_size,
                              hipStream_t stream) {
  const float* x  = (const float*)d_in[0];
  const int*   ei = (const int*)d_in[1];
  const float* ew = (const float*)d_in[2];
  const float* W1 = (const float*)d_in[3];
  const float* b1 = (const float*)d_in[4];
  const float* W2 = (const float*)d_in[5];
  const float* b2 = (const float*)d_in[6];
  float* out = (float*)d_out;

  // workspace layout (~22.5 MB)
  unsigned short* h1b      = (unsigned short*)d_ws;                    // N*64 bf16, 8MB
  unsigned*       g32u     = (unsigned*)(h1b + (size_t)N_NODES * 64);  // N*16 uint, 4MB
  unsigned*       val2     = g32u + (size_t)N_NODES * 16;              // 1M uint, 4MB
  unsigned*       sortedc  = val2 + (size_t)N_EDGES;                   // NB*CAP uint, 4.7MB
  unsigned*       offs_p   = sortedc + (size_t)NB * CAP;               // N packed CSR
  unsigned*       cnt_mat  = offs_p + N_NODES;                         // 256x256 u32
  unsigned*       lofs_mat = cnt_mat + (size_t)BLK_A * NB;             // 256x256 u32
  unsigned char*  key2     = (unsigned char*)(lofs_mat + (size_t)BLK_A * NB); // 1M bytes

  binpass_gemm1<<<BLK_A + GEMM_BLK, 256, 0, stream>>>(ei, ew, val2, key2, cnt_mat,
                                                      lofs_mat, x, W1, h1b);
  sortagg1<<<NB, 1024, 0, stream>>>(cnt_mat, lofs_mat, val2, key2, sortedc, offs_p,
                                    h1b, b1, W2, g32u);
  aggregate2<<<N_NODES / 16, 256, 0, stream>>>(offs_p, sortedc, g32u, b2, out);
}